// Round 7
// baseline (477.162 us; speedup 1.0000x reference)
//
#include <hip/hip_runtime.h>

#define B_ 4
#define C_ 64
#define F_ 128
#define T_ 128
#define K_ 8
#define H_ 32
#define S_ 121   // T - K + 1
#define N_ 512   // B * F
#define G_ 128   // 4 * H
#define CK_ 512  // C * K

typedef __attribute__((ext_vector_type(8))) short short8;
typedef __attribute__((ext_vector_type(4))) float f32x4;
union FragU { uint4 u; short8 s; };

__device__ __forceinline__ unsigned int pk2(float a, float b){   // RNE f32->bf16 pair
  unsigned int ua = __float_as_uint(a); ua += 0x7fffu + ((ua>>16)&1u);
  unsigned int ub = __float_as_uint(b); ub += 0x7fffu + ((ub>>16)&1u);
  return (ua>>16) | (ub & 0xffff0000u);
}
__device__ __forceinline__ unsigned short bfu(float a){          // RNE f32->bf16
  unsigned int ua = __float_as_uint(a); ua += 0x7fffu + ((ua>>16)&1u);
  return (unsigned short)(ua>>16);
}
__device__ __forceinline__ float ubf(unsigned short v){
  return __uint_as_float(((unsigned int)v) << 16);
}

// gx gate-pair interleaved slot: lane l of k_lstm reads one dword = (row l | row l+64 <<16)
__device__ __forceinline__ int gslot(int g){ return ((g & 63) << 1) | (g >> 6); }

// ---------------------------------------------------------------- instance norm stats
__global__ __launch_bounds__(256) void k_norm(const float* __restrict__ x,
    const float* __restrict__ gamma, const float* __restrict__ beta,
    float* __restrict__ scale, float* __restrict__ shift){
  int bc = blockIdx.x;
  const float* p = x + (size_t)bc * (F_*T_);
  float s = 0.f, q = 0.f;
  for (int i = threadIdx.x; i < F_*T_; i += 256){ float v = p[i]; s += v; q += v*v; }
  #pragma unroll
  for (int o = 32; o; o >>= 1){ s += __shfl_down(s, o); q += __shfl_down(q, o); }
  __shared__ float ss[4], qq[4];
  int w = threadIdx.x >> 6;
  if ((threadIdx.x & 63) == 0){ ss[w] = s; qq[w] = q; }
  __syncthreads();
  if (threadIdx.x == 0){
    s = ss[0]+ss[1]+ss[2]+ss[3]; q = qq[0]+qq[1]+qq[2]+qq[3];
    float mu  = s / (float)(F_*T_);
    float var = q / (float)(F_*T_) - mu*mu;
    if (var < 0.f) var = 0.f;
    int c = bc & (C_-1);
    float sc = gamma[c] * rsqrtf(var + 1e-5f);
    scale[bc] = sc;
    shift[bc] = beta[c] - mu * sc;
  }
}

// ---------------------------------------------------------------- weight f32 -> bf16
__global__ __launch_bounds__(256) void k_wcvt(const float* __restrict__ a,
    unsigned short* __restrict__ o, int nel){
  int i = blockIdx.x*256 + threadIdx.x;
  if (i < nel) o[i] = bfu(a[i]);
}
// conv weights: bf16 + reverse k within each 8-block (absorbs conv flip into GEMM)
__global__ __launch_bounds__(256) void k_wrev(const float* __restrict__ a,
    unsigned short* __restrict__ o, int nel){
  int i = blockIdx.x*256 + threadIdx.x;
  if (i < nel){ int j = (i & ~7) | (7 - (i & 7)); o[i] = bfu(a[j]); }
}

// ---------------------------------------------------------------- layer-0 projection, MFMA bf16
__global__ __launch_bounds__(256) void k_gx0(const float* __restrict__ x,
    const float* __restrict__ scale, const float* __restrict__ shift,
    const unsigned short* __restrict__ wb0, const float* __restrict__ bi,
    const float* __restrict__ bh, unsigned short* __restrict__ gx){
  __shared__ unsigned int xsp[C_][136];     // packed bf16 pairs (t, t+1); t>=128 zero
  int n = blockIdx.x, b = n >> 7, f = n & 127;
  const float* xb = x + (size_t)b*C_*F_*T_ + (size_t)f*T_;
  for (int i = threadIdx.x; i < C_*136; i += 256){
    int c = i / 136, t = i - c*136;
    float sc = scale[b*C_+c], sh = shift[b*C_+c];
    float v0 = (t   < T_) ? xb[(size_t)c*F_*T_ + t  ]*sc + sh : 0.f;
    float v1 = (t+1 < T_) ? xb[(size_t)c*F_*T_ + t+1]*sc + sh : 0.f;
    xsp[c][t] = pk2(v0, v1);
  }
  __syncthreads();
  int lane = threadIdx.x & 63, wv = threadIdx.x >> 6;
  int ln = lane & 15, quad = lane >> 4;
  int g256[4]; f32x4 acc[8][4];
  #pragma unroll
  for (int gi = 0; gi < 4; ++gi){
    g256[gi] = (wv*4 + gi)*16 + ln;
    float bv = bi[g256[gi]] + bh[g256[gi]];
    #pragma unroll
    for (int st = 0; st < 8; ++st) acc[st][gi] = (f32x4){bv, bv, bv, bv};
  }
  for (int kb = 0; kb < 16; ++kb){
    FragU bfr[4];
    #pragma unroll
    for (int gi = 0; gi < 4; ++gi)
      bfr[gi].u = *(const uint4*)(wb0 + (size_t)g256[gi]*CK_ + kb*32 + quad*8);
    #pragma unroll
    for (int st = 0; st < 8; ++st){
      FragU a;
      const unsigned int* rp = &xsp[kb*4 + quad][st*16 + ln];
      a.u.x = rp[0]; a.u.y = rp[2]; a.u.z = rp[4]; a.u.w = rp[6];
      #pragma unroll
      for (int gi = 0; gi < 4; ++gi)
        acc[st][gi] = __builtin_amdgcn_mfma_f32_16x16x32_bf16(a.s, bfr[gi].s, acc[st][gi], 0, 0, 0);
    }
  }
  #pragma unroll
  for (int st = 0; st < 8; ++st)
    #pragma unroll
    for (int gi = 0; gi < 4; ++gi){
      int d = g256[gi] >> 7, g = g256[gi] & 127;
      #pragma unroll
      for (int r = 0; r < 4; ++r){
        int s = st*16 + quad*4 + r;
        if (s < S_)
          gx[((size_t)(d*N_ + n)*S_ + s)*G_ + gslot(g)] = bfu(acc[st][gi][r]);
      }
    }
}

// ---------------------------------------------------------------- layers 1..3 projection, MFMA bf16
__global__ __launch_bounds__(256) void k_gxl(const unsigned short* __restrict__ hin,
    const unsigned short* __restrict__ wlb, const float* __restrict__ bi,
    const float* __restrict__ bh, unsigned short* __restrict__ gx){
  __shared__ unsigned int hsp[32][132];     // [i_pair][s], s>=121 zero
  int n = blockIdx.x;
  const unsigned int* hu = (const unsigned int*)hin;
  for (int i = threadIdx.x; i < 32*128; i += 256){
    int s = i >> 5, ip = i & 31;
    hsp[ip][s] = (s < S_) ? hu[((size_t)n*S_ + s)*32 + ip] : 0u;
  }
  __syncthreads();
  int lane = threadIdx.x & 63, wv = threadIdx.x >> 6;
  int ln = lane & 15, quad = lane >> 4;
  int g256[4]; f32x4 acc[8][4];
  #pragma unroll
  for (int gi = 0; gi < 4; ++gi){
    g256[gi] = (wv*4 + gi)*16 + ln;
    float bv = bi[g256[gi]] + bh[g256[gi]];
    #pragma unroll
    for (int st = 0; st < 8; ++st) acc[st][gi] = (f32x4){bv, bv, bv, bv};
  }
  #pragma unroll
  for (int kb = 0; kb < 2; ++kb){
    FragU bfr[4];
    #pragma unroll
    for (int gi = 0; gi < 4; ++gi)
      bfr[gi].u = *(const uint4*)(wlb + (size_t)g256[gi]*64 + kb*32 + quad*8);
    #pragma unroll
    for (int st = 0; st < 8; ++st){
      FragU a;
      int ipb = kb*16 + quad*4, srow = st*16 + ln;
      a.u.x = hsp[ipb+0][srow]; a.u.y = hsp[ipb+1][srow];
      a.u.z = hsp[ipb+2][srow]; a.u.w = hsp[ipb+3][srow];
      #pragma unroll
      for (int gi = 0; gi < 4; ++gi)
        acc[st][gi] = __builtin_amdgcn_mfma_f32_16x16x32_bf16(a.s, bfr[gi].s, acc[st][gi], 0, 0, 0);
    }
  }
  #pragma unroll
  for (int st = 0; st < 8; ++st)
    #pragma unroll
    for (int gi = 0; gi < 4; ++gi){
      int d = g256[gi] >> 7, g = g256[gi] & 127;
      #pragma unroll
      for (int r = 0; r < 4; ++r){
        int s = st*16 + quad*4 + r;
        if (s < S_)
          gx[((size_t)(d*N_ + n)*S_ + s)*G_ + gslot(g)] = bfu(acc[st][gi][r]);
      }
    }
}

// ---------------------------------------------------------------- LSTM: one wave per (n,dir)
// branch-free, 8-deep dword prefetch ring; lane l reads one dword = (row l | row l+64<<16)
// amdgpu_waves_per_eu(1): allocator targets 1 wave/EU (512-VGPR budget).
// asm pins: weight values defined by opaque asm -> cannot be sunk/rematerialized
// into the loop (round-5/6 showed the sinking heuristic ignores launch_bounds).
__global__ __launch_bounds__(64)
__attribute__((amdgpu_waves_per_eu(1)))
void k_lstm(const unsigned short* __restrict__ gx,
    const float* __restrict__ whh, unsigned short* __restrict__ hout){
  int blk = blockIdx.x;
  int n = blk & (N_-1), d = blk >> 9;
  int lane = threadIdx.x;
  int j = lane & 31, hi = lane >> 5;
  float w1[32], w2[32];
  const float* wr1 = whh + (size_t)(d*G_ + lane)*H_;
  const float* wr2 = whh + (size_t)(d*G_ + lane + 64)*H_;
  #pragma unroll
  for (int q = 0; q < 8; ++q){
    float4 aa = *(const float4*)(wr1 + q*4);
    float4 bb = *(const float4*)(wr2 + q*4);
    w1[q*4+0]=aa.x; w1[q*4+1]=aa.y; w1[q*4+2]=aa.z; w1[q*4+3]=aa.w;
    w2[q*4+0]=bb.x; w2[q*4+1]=bb.y; w2[q*4+2]=bb.z; w2[q*4+3]=bb.w;
  }
  #pragma unroll
  for (int k = 0; k < 32; ++k){               // pin weights in VGPRs
    asm volatile("" : "+v"(w1[k]));
    asm volatile("" : "+v"(w2[k]));
  }
  const unsigned int* gxu = (const unsigned int*)gx;
  ptrdiff_t stride = d ? -64 : 64;
  const unsigned int* p0 = gxu + ((size_t)(d*N_ + n)*S_ + (d ? (S_-1) : 0))*64 + lane;
  unsigned int buf[8];
  #pragma unroll
  for (int u = 0; u < 8; ++u) buf[u] = p0[stride*u];
  const unsigned int* pf = p0 + stride*8;   // overfetch past chain end stays inside gx buffer

  ptrdiff_t hstride = d ? -64 : 64;
  unsigned short* hop = hout + (size_t)n*S_*64 + (d ? (size_t)(S_-1)*64 : 0) + d*32 + j;

  float hv = 0.f, c = 0.f;
  auto rl = [&](int k)->float{
    return __uint_as_float(__builtin_amdgcn_readlane(__float_as_uint(hv), k));
  };
  auto step = [&](unsigned int cur){
    float acc1 = __uint_as_float(cur << 16);          // row lane     (i / f)
    float acc2 = __uint_as_float(cur & 0xffff0000u);  // row lane+64  (g / o)
    float s1a = acc1, s1b = 0.f, s1c = 0.f, s1d = 0.f;
    float s2a = acc2, s2b = 0.f, s2c = 0.f, s2d = 0.f;
    #pragma unroll
    for (int k = 0; k < 32; k += 4){
      float h0 = rl(k), h1 = rl(k+1), h2 = rl(k+2), h3 = rl(k+3);
      s1a += h0*w1[k];   s1b += h1*w1[k+1]; s1c += h2*w1[k+2]; s1d += h3*w1[k+3];
      s2a += h0*w2[k];   s2b += h1*w2[k+1]; s2c += h2*w2[k+2]; s2d += h3*w2[k+3];
    }
    acc1 = (s1a + s1b) + (s1c + s1d);
    acc2 = (s2a + s2b) + (s2c + s2d);
    float a1 = 1.f/(1.f + __expf(-acc1));            // sigmoid (i or f)
    float x2 = hi ? acc2 : 2.f*acc2;                 // shared-exp: o sigm / g tanh
    float tt = 1.f/(1.f + __expf(-x2));
    float a2 = hi ? tt : 2.f*tt - 1.f;
    float b1 = __shfl_xor(a1, 32);
    float b2 = __shfl_xor(a2, 32);
    float i_ = hi ? b1 : a1;
    float f_ = hi ? a1 : b1;
    float g_ = hi ? b2 : a2;
    float o_ = hi ? a2 : b2;
    c = f_*c + i_*g_;
    float tc = 1.f/(1.f + __expf(-2.f*c));
    hv = o_*(2.f*tc - 1.f);
    if (!hi) *hop = bfu(hv);
    hop += hstride;
  };

  for (int ob = 0; ob < 15; ++ob){        // steps 0..119
    #pragma unroll
    for (int u = 0; u < 8; ++u){
      unsigned int cur = buf[u];
      buf[u] = *pf; pf += stride;          // prefetch st+8 (overfetch harmless, never consumed)
      step(cur);
    }
  }
  step(buf[0]);                            // step 120 (loaded at st=112)
}

// ---------------------------------------------------------------- ConvTranspose via MFMA + bias + residual
__global__ __launch_bounds__(256) void k_conv(const unsigned short* __restrict__ hin,
    const unsigned short* __restrict__ wA, const float* __restrict__ bct,
    const float* __restrict__ x, float* __restrict__ out){
  __shared__ unsigned int hraw[S_][33];     // [s][ip] dwords, stride 33 (swizzle for transpose read)
  __shared__ unsigned int hp2[64][144];     // overlapping bf16 pairs [ci][col], col=t'+8, stride 144
  int n = blockIdx.x, b = n >> 7, f = n & 127;
  const unsigned int* hu = (const unsigned int*)hin + (size_t)n*S_*32;
  for (int i = threadIdx.x; i < S_*32; i += 256)
    hraw[i >> 5][i & 31] = hu[i];
  __syncthreads();
  const unsigned short* hr16 = (const unsigned short*)&hraw[0][0];  // u16 idx = s*66 + ci
  for (int it = threadIdx.x; it < 64*136; it += 256){
    int ci = it / 136, col = it - ci*136;
    int t0 = col - 8;
    unsigned int lo  = (t0 >= 0 && t0 < S_)     ? hr16[t0*66 + ci]     : 0u;
    unsigned int hi2 = (t0+1 >= 0 && t0+1 < S_) ? hr16[(t0+1)*66 + ci] : 0u;
    hp2[ci][col] = lo | (hi2 << 16);
  }
  __syncthreads();
  int lane = threadIdx.x & 63, wv = threadIdx.x >> 6;
  int ln = lane & 15, quad = lane >> 4;
  const unsigned short* wp = wA + (size_t)(wv*16 + ln)*512;
  f32x4 acc[8];
  #pragma unroll
  for (int nt = 0; nt < 8; ++nt) acc[nt] = (f32x4){0.f,0.f,0.f,0.f};
  for (int kb = 0; kb < 16; ++kb){
    FragU afr; afr.u = *(const uint4*)(wp + kb*32 + quad*8);
    int ci = kb*4 + quad;
    #pragma unroll
    for (int nt = 0; nt < 8; ++nt){
      FragU bfr;
      const unsigned int* rp = &hp2[ci][nt*16 + ln + 1];
      bfr.u.x = rp[0]; bfr.u.y = rp[2]; bfr.u.z = rp[4]; bfr.u.w = rp[6];
      acc[nt] = __builtin_amdgcn_mfma_f32_16x16x32_bf16(afr.s, bfr.s, acc[nt], 0, 0, 0);
    }
  }
  float bb[4];
  #pragma unroll
  for (int r = 0; r < 4; ++r) bb[r] = bct[wv*16 + quad*4 + r];
  #pragma unroll
  for (int nt = 0; nt < 8; ++nt)
    #pragma unroll
    for (int r = 0; r < 4; ++r){
      int co = wv*16 + quad*4 + r, t = nt*16 + ln;
      size_t idx = ((size_t)(b*64 + co)*128 + f)*128 + t;
      out[idx] = acc[nt][r] + bb[r] + x[idx];
    }
}

// ----------------------------------------------------------------
extern "C" void kernel_launch(void* const* d_in, const int* in_sizes, int n_in,
                              void* d_out, int out_size, void* d_ws, size_t ws_size,
                              hipStream_t stream){
  const float* x     = (const float*)d_in[0];
  const float* gamma = (const float*)d_in[1];
  const float* beta  = (const float*)d_in[2];
  const float* wih0  = (const float*)d_in[3];   // [2,128,512]
  const float* whh0  = (const float*)d_in[4];   // [2,128,32]
  const float* bih0  = (const float*)d_in[5];
  const float* bhh0  = (const float*)d_in[6];
  const float* wih   = (const float*)d_in[7];   // [3,2,128,64]
  const float* whh   = (const float*)d_in[8];   // [3,2,128,32]
  const float* bih   = (const float*)d_in[9];
  const float* bhh   = (const float*)d_in[10];
  const float* wct   = (const float*)d_in[11];  // [64,64,8]
  const float* bct   = (const float*)d_in[12];
  float* out = (float*)d_out;

  char* wsb = (char*)d_ws;
  float*          scale = (float*)(wsb);                       // 1 KB
  float*          shift = (float*)(wsb + 1024);                // 1 KB
  unsigned short* gx    = (unsigned short*)(wsb + 2048);       // 31,719,424 B
  unsigned short* hA    = (unsigned short*)(wsb + 31721472);   // 7,929,856 B
  unsigned short* hB    = (unsigned short*)(wsb + 39651328);   // 7,929,856 B
  unsigned short* wb0   = (unsigned short*)(wsb + 47581184);   // 262,144 B
  unsigned short* wlb   = (unsigned short*)(wsb + 47843328);   // 98,304 B
  unsigned short* wcv   = (unsigned short*)(wsb + 47941632);   // 65,536 B  (~48.0 MB total)

  k_norm<<<256, 256, 0, stream>>>(x, gamma, beta, scale, shift);
  k_wcvt<<<512, 256, 0, stream>>>(wih0, wb0, 2*G_*CK_);
  k_wcvt<<<192, 256, 0, stream>>>(wih,  wlb, 3*2*G_*64);
  k_wrev<<<128, 256, 0, stream>>>(wct,  wcv, 64*512);
  k_gx0 <<<512, 256, 0, stream>>>(x, scale, shift, wb0, bih0, bhh0, gx);
  k_lstm<<<1024, 64, 0, stream>>>(gx, whh0, hA);
  unsigned short* hp = hA; unsigned short* hn = hB;
  for (int l = 0; l < 3; ++l){
    k_gxl <<<512, 256, 0, stream>>>(hp, wlb + (size_t)l*2*G_*64,
                                    bih + (size_t)l*2*G_, bhh + (size_t)l*2*G_, gx);
    k_lstm<<<1024, 64, 0, stream>>>(gx, whh + (size_t)l*2*G_*H_, hn);
    unsigned short* tmp = hp; hp = hn; hn = tmp;
  }
  k_conv<<<512, 256, 0, stream>>>(hp, wcv, bct, x, out);
}

// Round 8
// 419.485 us; speedup vs baseline: 1.1375x; 1.1375x over previous
//
#include <hip/hip_runtime.h>

#define B_ 4
#define C_ 64
#define F_ 128
#define T_ 128
#define K_ 8
#define H_ 32
#define S_ 121   // T - K + 1
#define N_ 512   // B * F
#define G_ 128   // 4 * H
#define CK_ 512  // C * K

typedef __attribute__((ext_vector_type(8))) short short8;
typedef __attribute__((ext_vector_type(4))) float f32x4;
union FragU { uint4 u; short8 s; };

__device__ __forceinline__ unsigned int pk2(float a, float b){   // RNE f32->bf16 pair
  unsigned int ua = __float_as_uint(a); ua += 0x7fffu + ((ua>>16)&1u);
  unsigned int ub = __float_as_uint(b); ub += 0x7fffu + ((ub>>16)&1u);
  return (ua>>16) | (ub & 0xffff0000u);
}
__device__ __forceinline__ unsigned short bfu(float a){          // RNE f32->bf16
  unsigned int ua = __float_as_uint(a); ua += 0x7fffu + ((ua>>16)&1u);
  return (unsigned short)(ua>>16);
}
__device__ __forceinline__ float ubf(unsigned short v){
  return __uint_as_float(((unsigned int)v) << 16);
}

// gx gate-pair interleaved slot: lane l of k_lstm reads one dword = (row l | row l+64 <<16)
__device__ __forceinline__ int gslot(int g){ return ((g & 63) << 1) | (g >> 6); }

// ---------------------------------------------------------------- instance norm stats
__global__ __launch_bounds__(256) void k_norm(const float* __restrict__ x,
    const float* __restrict__ gamma, const float* __restrict__ beta,
    float* __restrict__ scale, float* __restrict__ shift){
  int bc = blockIdx.x;
  const float* p = x + (size_t)bc * (F_*T_);
  float s = 0.f, q = 0.f;
  for (int i = threadIdx.x; i < F_*T_; i += 256){ float v = p[i]; s += v; q += v*v; }
  #pragma unroll
  for (int o = 32; o; o >>= 1){ s += __shfl_down(s, o); q += __shfl_down(q, o); }
  __shared__ float ss[4], qq[4];
  int w = threadIdx.x >> 6;
  if ((threadIdx.x & 63) == 0){ ss[w] = s; qq[w] = q; }
  __syncthreads();
  if (threadIdx.x == 0){
    s = ss[0]+ss[1]+ss[2]+ss[3]; q = qq[0]+qq[1]+qq[2]+qq[3];
    float mu  = s / (float)(F_*T_);
    float var = q / (float)(F_*T_) - mu*mu;
    if (var < 0.f) var = 0.f;
    int c = bc & (C_-1);
    float sc = gamma[c] * rsqrtf(var + 1e-5f);
    scale[bc] = sc;
    shift[bc] = beta[c] - mu * sc;
  }
}

// ---------------------------------------------------------------- weight f32 -> bf16
__global__ __launch_bounds__(256) void k_wcvt(const float* __restrict__ a,
    unsigned short* __restrict__ o, int nel){
  int i = blockIdx.x*256 + threadIdx.x;
  if (i < nel) o[i] = bfu(a[i]);
}
// conv weights: bf16 + reverse k within each 8-block (absorbs conv flip into GEMM)
__global__ __launch_bounds__(256) void k_wrev(const float* __restrict__ a,
    unsigned short* __restrict__ o, int nel){
  int i = blockIdx.x*256 + threadIdx.x;
  if (i < nel){ int j = (i & ~7) | (7 - (i & 7)); o[i] = bfu(a[j]); }
}

// ---------------------------------------------------------------- layer-0 projection, MFMA bf16
__global__ __launch_bounds__(256) void k_gx0(const float* __restrict__ x,
    const float* __restrict__ scale, const float* __restrict__ shift,
    const unsigned short* __restrict__ wb0, const float* __restrict__ bi,
    const float* __restrict__ bh, unsigned short* __restrict__ gx){
  __shared__ unsigned int xsp[C_][136];     // packed bf16 pairs (t, t+1); t>=128 zero
  int n = blockIdx.x, b = n >> 7, f = n & 127;
  const float* xb = x + (size_t)b*C_*F_*T_ + (size_t)f*T_;
  for (int i = threadIdx.x; i < C_*136; i += 256){
    int c = i / 136, t = i - c*136;
    float sc = scale[b*C_+c], sh = shift[b*C_+c];
    float v0 = (t   < T_) ? xb[(size_t)c*F_*T_ + t  ]*sc + sh : 0.f;
    float v1 = (t+1 < T_) ? xb[(size_t)c*F_*T_ + t+1]*sc + sh : 0.f;
    xsp[c][t] = pk2(v0, v1);
  }
  __syncthreads();
  int lane = threadIdx.x & 63, wv = threadIdx.x >> 6;
  int ln = lane & 15, quad = lane >> 4;
  int g256[4]; f32x4 acc[8][4];
  #pragma unroll
  for (int gi = 0; gi < 4; ++gi){
    g256[gi] = (wv*4 + gi)*16 + ln;
    float bv = bi[g256[gi]] + bh[g256[gi]];
    #pragma unroll
    for (int st = 0; st < 8; ++st) acc[st][gi] = (f32x4){bv, bv, bv, bv};
  }
  for (int kb = 0; kb < 16; ++kb){
    FragU bfr[4];
    #pragma unroll
    for (int gi = 0; gi < 4; ++gi)
      bfr[gi].u = *(const uint4*)(wb0 + (size_t)g256[gi]*CK_ + kb*32 + quad*8);
    #pragma unroll
    for (int st = 0; st < 8; ++st){
      FragU a;
      const unsigned int* rp = &xsp[kb*4 + quad][st*16 + ln];
      a.u.x = rp[0]; a.u.y = rp[2]; a.u.z = rp[4]; a.u.w = rp[6];
      #pragma unroll
      for (int gi = 0; gi < 4; ++gi)
        acc[st][gi] = __builtin_amdgcn_mfma_f32_16x16x32_bf16(a.s, bfr[gi].s, acc[st][gi], 0, 0, 0);
    }
  }
  #pragma unroll
  for (int st = 0; st < 8; ++st)
    #pragma unroll
    for (int gi = 0; gi < 4; ++gi){
      int d = g256[gi] >> 7, g = g256[gi] & 127;
      #pragma unroll
      for (int r = 0; r < 4; ++r){
        int s = st*16 + quad*4 + r;
        if (s < S_)
          gx[((size_t)(d*N_ + n)*S_ + s)*G_ + gslot(g)] = bfu(acc[st][gi][r]);
      }
    }
}

// ---------------------------------------------------------------- layers 1..3 projection, MFMA bf16
// hin layout: [n][ci][128] bf16, st-indexed (d=1 half time-reversed: t = 120 - st)
__global__ __launch_bounds__(256) void k_gxl(const unsigned short* __restrict__ hin,
    const unsigned short* __restrict__ wlb, const float* __restrict__ bi,
    const float* __restrict__ bh, unsigned short* __restrict__ gx){
  __shared__ unsigned int hrawL[64][65];    // raw rows [ci][64 dwords]
  __shared__ unsigned int hsp[32][132];     // [ci_pair][s], s>=121 zero
  int n = blockIdx.x;
  const unsigned int* hu = (const unsigned int*)hin + (size_t)n*64*64;
  for (int i = threadIdx.x; i < 64*64; i += 256){
    int ci = i >> 6, k = i & 63;
    hrawL[ci][k] = hu[ci*64 + k];
  }
  __syncthreads();
  const unsigned short* rawu = (const unsigned short*)&hrawL[0][0];  // row stride 130 u16
  for (int i = threadIdx.x; i < 32*128; i += 256){
    int srow = i >> 5, ip = i & 31;
    unsigned int v = 0;
    if (srow <= 120){
      int st = (ip < 16) ? srow : (120 - srow);
      v = (unsigned int)rawu[(2*ip)*130 + st] | ((unsigned int)rawu[(2*ip+1)*130 + st] << 16);
    }
    hsp[ip][srow] = v;
  }
  __syncthreads();
  int lane = threadIdx.x & 63, wv = threadIdx.x >> 6;
  int ln = lane & 15, quad = lane >> 4;
  int g256[4]; f32x4 acc[8][4];
  #pragma unroll
  for (int gi = 0; gi < 4; ++gi){
    g256[gi] = (wv*4 + gi)*16 + ln;
    float bv = bi[g256[gi]] + bh[g256[gi]];
    #pragma unroll
    for (int st = 0; st < 8; ++st) acc[st][gi] = (f32x4){bv, bv, bv, bv};
  }
  #pragma unroll
  for (int kb = 0; kb < 2; ++kb){
    FragU bfr[4];
    #pragma unroll
    for (int gi = 0; gi < 4; ++gi)
      bfr[gi].u = *(const uint4*)(wlb + (size_t)g256[gi]*64 + kb*32 + quad*8);
    #pragma unroll
    for (int st = 0; st < 8; ++st){
      FragU a;
      int ipb = kb*16 + quad*4, srow = st*16 + ln;
      a.u.x = hsp[ipb+0][srow]; a.u.y = hsp[ipb+1][srow];
      a.u.z = hsp[ipb+2][srow]; a.u.w = hsp[ipb+3][srow];
      #pragma unroll
      for (int gi = 0; gi < 4; ++gi)
        acc[st][gi] = __builtin_amdgcn_mfma_f32_16x16x32_bf16(a.s, bfr[gi].s, acc[st][gi], 0, 0, 0);
    }
  }
  #pragma unroll
  for (int st = 0; st < 8; ++st)
    #pragma unroll
    for (int gi = 0; gi < 4; ++gi){
      int d = g256[gi] >> 7, g = g256[gi] & 127;
      #pragma unroll
      for (int r = 0; r < 4; ++r){
        int s = st*16 + quad*4 + r;
        if (s < S_)
          gx[((size_t)(d*N_ + n)*S_ + s)*G_ + gslot(g)] = bfu(acc[st][gi][r]);
      }
    }
}

// ---------------------------------------------------------------- LSTM: one wave per (n,dir)
// Grouped K-stream: 8 gx loads issued once per 8 steps, double-buffered -> any
// conservative vmcnt drain costs one latency per GROUP, not per step (round-7 fix).
// Stores batched: 4 packed dwords per 8 steps. hout layout [n][ci][128] st-indexed.
__global__ __launch_bounds__(64)
__attribute__((amdgpu_waves_per_eu(1, 1)))
void k_lstm(const unsigned short* __restrict__ gx,
    const float* __restrict__ whh, unsigned short* __restrict__ hout){
  int blk = blockIdx.x;
  int n = blk & (N_-1), d = blk >> 9;
  int lane = threadIdx.x;
  int j = lane & 31, hi = lane >> 5;
  float w1[32], w2[32];
  const float* wr1 = whh + (size_t)(d*G_ + lane)*H_;
  const float* wr2 = whh + (size_t)(d*G_ + lane + 64)*H_;
  #pragma unroll
  for (int q = 0; q < 8; ++q){
    float4 aa = *(const float4*)(wr1 + q*4);
    float4 bb = *(const float4*)(wr2 + q*4);
    w1[q*4+0]=aa.x; w1[q*4+1]=aa.y; w1[q*4+2]=aa.z; w1[q*4+3]=aa.w;
    w2[q*4+0]=bb.x; w2[q*4+1]=bb.y; w2[q*4+2]=bb.z; w2[q*4+3]=bb.w;
  }
  #pragma unroll
  for (int k = 0; k < 32; ++k){               // pin weights (no sink/remat)
    asm volatile("" : "+v"(w1[k]));
    asm volatile("" : "+v"(w2[k]));
  }
  const unsigned int* gxu = (const unsigned int*)gx;
  ptrdiff_t stride = d ? -64 : 64;
  const unsigned int* p0 = gxu + ((size_t)(d*N_ + n)*S_ + (d ? (S_-1) : 0))*64 + lane;
  unsigned short* hop = hout + ((size_t)n*64 + d*32 + j)*128;   // st-indexed row

  float hv = 0.f, c = 0.f;
  unsigned int hgd[4];
  auto rl = [&](int k)->float{
    return __uint_as_float(__builtin_amdgcn_readlane(__float_as_uint(hv), k));
  };
  auto step = [&](unsigned int cur, int u){
    float acc1 = __uint_as_float(cur << 16);          // row lane     (i / f)
    float acc2 = __uint_as_float(cur & 0xffff0000u);  // row lane+64  (g / o)
    float s1a = acc1, s1b = 0.f, s1c = 0.f, s1d = 0.f;
    float s2a = acc2, s2b = 0.f, s2c = 0.f, s2d = 0.f;
    #pragma unroll
    for (int k = 0; k < 32; k += 4){
      float h0 = rl(k), h1 = rl(k+1), h2 = rl(k+2), h3 = rl(k+3);
      s1a += h0*w1[k];   s1b += h1*w1[k+1]; s1c += h2*w1[k+2]; s1d += h3*w1[k+3];
      s2a += h0*w2[k];   s2b += h1*w2[k+1]; s2c += h2*w2[k+2]; s2d += h3*w2[k+3];
    }
    acc1 = (s1a + s1b) + (s1c + s1d);
    acc2 = (s2a + s2b) + (s2c + s2d);
    float a1 = 1.f/(1.f + __expf(-acc1));            // sigmoid (i or f)
    float x2 = hi ? acc2 : 2.f*acc2;                 // shared-exp: o sigm / g tanh
    float tt = 1.f/(1.f + __expf(-x2));
    float a2 = hi ? tt : 2.f*tt - 1.f;
    float b1 = __shfl_xor(a1, 32);
    float b2 = __shfl_xor(a2, 32);
    float i_ = hi ? b1 : a1;
    float f_ = hi ? a1 : b1;
    float g_ = hi ? b2 : a2;
    float o_ = hi ? a2 : b2;
    c = f_*c + i_*g_;
    float tc = 1.f/(1.f + __expf(-2.f*c));
    hv = o_*(2.f*tc - 1.f);
    unsigned int hb = (unsigned int)bfu(hv);
    if ((u & 1) == 0) hgd[u >> 1] = hb;
    else              hgd[u >> 1] |= hb << 16;
  };

  unsigned int bufA[8], bufB[8];
  #pragma unroll
  for (int u = 0; u < 8; ++u) bufA[u] = p0[stride*u];          // group 0

  for (int gg = 0; gg < 7; ++gg){            // groups 0..13 (steps 0..111)
    int g0 = gg*2;
    #pragma unroll
    for (int u = 0; u < 8; ++u) bufB[u] = p0[stride*(8*(g0+1) + u)];
    #pragma unroll
    for (int u = 0; u < 8; ++u) step(bufA[u], u);
    if (!hi) *(uint4*)(hop + 8*g0) = (uint4){hgd[0], hgd[1], hgd[2], hgd[3]};
    #pragma unroll
    for (int u = 0; u < 8; ++u) bufA[u] = p0[stride*(8*(g0+2) + u)];
    #pragma unroll
    for (int u = 0; u < 8; ++u) step(bufB[u], u);
    if (!hi) *(uint4*)(hop + 8*(g0+1)) = (uint4){hgd[0], hgd[1], hgd[2], hgd[3]};
  }
  // group 14 (steps 112..119), prefetch st=120
  bufB[0] = p0[stride*120];
  #pragma unroll
  for (int u = 0; u < 8; ++u) step(bufA[u], u);
  if (!hi) *(uint4*)(hop + 112) = (uint4){hgd[0], hgd[1], hgd[2], hgd[3]};
  // step 120
  step(bufB[0], 0);
  if (!hi) hop[120] = (unsigned short)(hgd[0] & 0xffffu);
}

// ---------------------------------------------------------------- ConvTranspose via MFMA + bias + residual
// hin layout: [n][ci][128] bf16 st-indexed (ci>=32 time-reversed: t = 120 - st)
__global__ __launch_bounds__(256) void k_conv(const unsigned short* __restrict__ hin,
    const unsigned short* __restrict__ wA, const float* __restrict__ bct,
    const float* __restrict__ x, float* __restrict__ out){
  __shared__ unsigned int hrawL[64][65];    // raw rows [ci][64 dwords]
  __shared__ unsigned int hp2[64][144];     // overlapping bf16 pairs [ci][col], col=t'+8
  int n = blockIdx.x, b = n >> 7, f = n & 127;
  const unsigned int* hu = (const unsigned int*)hin + (size_t)n*64*64;
  for (int i = threadIdx.x; i < 64*64; i += 256){
    int ci = i >> 6, k = i & 63;
    hrawL[ci][k] = hu[ci*64 + k];
  }
  __syncthreads();
  const unsigned short* rawu = (const unsigned short*)&hrawL[0][0];  // row stride 130 u16
  for (int it = threadIdx.x; it < 64*136; it += 256){
    int ci = it / 136, col = it - ci*136;
    int t0 = col - 8;
    int i0 = (ci < 32) ? t0 : (120 - t0);
    int i1 = (ci < 32) ? (t0+1) : (119 - t0);
    unsigned int lo  = (t0   >= 0 && t0   <= 120) ? rawu[ci*130 + i0] : 0u;
    unsigned int hi2 = (t0+1 >= 0 && t0+1 <= 120) ? rawu[ci*130 + i1] : 0u;
    hp2[ci][col] = lo | (hi2 << 16);
  }
  __syncthreads();
  int lane = threadIdx.x & 63, wv = threadIdx.x >> 6;
  int ln = lane & 15, quad = lane >> 4;
  const unsigned short* wp = wA + (size_t)(wv*16 + ln)*512;
  f32x4 acc[8];
  #pragma unroll
  for (int nt = 0; nt < 8; ++nt) acc[nt] = (f32x4){0.f,0.f,0.f,0.f};
  for (int kb = 0; kb < 16; ++kb){
    FragU afr; afr.u = *(const uint4*)(wp + kb*32 + quad*8);
    int ci = kb*4 + quad;
    #pragma unroll
    for (int nt = 0; nt < 8; ++nt){
      FragU bfr;
      const unsigned int* rp = &hp2[ci][nt*16 + ln + 1];
      bfr.u.x = rp[0]; bfr.u.y = rp[2]; bfr.u.z = rp[4]; bfr.u.w = rp[6];
      acc[nt] = __builtin_amdgcn_mfma_f32_16x16x32_bf16(afr.s, bfr.s, acc[nt], 0, 0, 0);
    }
  }
  float bb[4];
  #pragma unroll
  for (int r = 0; r < 4; ++r) bb[r] = bct[wv*16 + quad*4 + r];
  #pragma unroll
  for (int nt = 0; nt < 8; ++nt)
    #pragma unroll
    for (int r = 0; r < 4; ++r){
      int co = wv*16 + quad*4 + r, t = nt*16 + ln;
      size_t idx = ((size_t)(b*64 + co)*128 + f)*128 + t;
      out[idx] = acc[nt][r] + bb[r] + x[idx];
    }
}

// ----------------------------------------------------------------
extern "C" void kernel_launch(void* const* d_in, const int* in_sizes, int n_in,
                              void* d_out, int out_size, void* d_ws, size_t ws_size,
                              hipStream_t stream){
  const float* x     = (const float*)d_in[0];
  const float* gamma = (const float*)d_in[1];
  const float* beta  = (const float*)d_in[2];
  const float* wih0  = (const float*)d_in[3];   // [2,128,512]
  const float* whh0  = (const float*)d_in[4];   // [2,128,32]
  const float* bih0  = (const float*)d_in[5];
  const float* bhh0  = (const float*)d_in[6];
  const float* wih   = (const float*)d_in[7];   // [3,2,128,64]
  const float* whh   = (const float*)d_in[8];   // [3,2,128,32]
  const float* bih   = (const float*)d_in[9];
  const float* bhh   = (const float*)d_in[10];
  const float* wct   = (const float*)d_in[11];  // [64,64,8]
  const float* bct   = (const float*)d_in[12];
  float* out = (float*)d_out;

  char* wsb = (char*)d_ws;
  float*          scale = (float*)(wsb);                       // 1 KB
  float*          shift = (float*)(wsb + 1024);                // 1 KB
  unsigned short* gx    = (unsigned short*)(wsb + 2048);       // 31,719,424 B
  unsigned short* hA    = (unsigned short*)(wsb + 31721472);   // 512*64*128*2 = 8,388,608 B
  unsigned short* hB    = (unsigned short*)(wsb + 40110080);   // 8,388,608 B
  unsigned short* wb0   = (unsigned short*)(wsb + 48498688);   // 262,144 B
  unsigned short* wlb   = (unsigned short*)(wsb + 48760832);   // 98,304 B
  unsigned short* wcv   = (unsigned short*)(wsb + 48859136);   // 65,536 B (~48.9 MB total)

  k_norm<<<256, 256, 0, stream>>>(x, gamma, beta, scale, shift);
  k_wcvt<<<512, 256, 0, stream>>>(wih0, wb0, 2*G_*CK_);
  k_wcvt<<<192, 256, 0, stream>>>(wih,  wlb, 3*2*G_*64);
  k_wrev<<<128, 256, 0, stream>>>(wct,  wcv, 64*512);
  k_gx0 <<<512, 256, 0, stream>>>(x, scale, shift, wb0, bih0, bhh0, gx);
  k_lstm<<<1024, 64, 0, stream>>>(gx, whh0, hA);
  unsigned short* hp = hA; unsigned short* hn = hB;
  for (int l = 0; l < 3; ++l){
    k_gxl <<<512, 256, 0, stream>>>(hp, wlb + (size_t)l*2*G_*64,
                                    bih + (size_t)l*2*G_, bhh + (size_t)l*2*G_, gx);
    k_lstm<<<1024, 64, 0, stream>>>(gx, whh + (size_t)l*2*G_*H_, hn);
    unsigned short* tmp = hp; hp = hn; hn = tmp;
  }
  k_conv<<<512, 256, 0, stream>>>(hp, wcv, bct, x, out);
}